// Round 6
// baseline (218.032 us; speedup 1.0000x reference)
//
#include <hip/hip_runtime.h>
#include <cstdint>
#include <cstddef>

// ---------------------------------------------------------------------------
// Conv2d 3x3 s1 p1 on 16-bit fixed-point (12 frac bits) quantized operands.
// x: (32,128,56,56) f32   w: (256,128,3,3) f32   out: (32,256,56,56) f32
// Implicit GEMM M=256, N=100352, K=1152.
// R6: A (weights, 576 KiB, L2-resident) loaded DIRECT to registers with a
// 2-K-step ping-pong (raE/raO) -> RAW slack of a full 2 K-steps (fixes R4's
// zero-distance reload). Weights pre-shuffled so each A-load instruction is a
// contiguous 1KB wave read (ideal coalescing). LDS holds only B: tile
// 256x128, 784 blocks, 8 waves, per-wave 64x64 output (acc=64 VGPR).
// B path identical to R3: XOR-8 chunk swizzle, gload_lds, counted vmcnt(10)
// (= 8 A-loads + 2 B-stages newer than the awaited buffer). 2 barriers/kt.
// ---------------------------------------------------------------------------

typedef __attribute__((ext_vector_type(8))) short short8;
typedef __attribute__((ext_vector_type(4))) float floatx4;

#define NIMG 32
#define CIN  128
#define HW   56
#define KOUT 256
#define HP   58                                   // padded H/W
#define XPAD_ELEMS ((size_t)NIMG * HP * HP * CIN) // 13,778,944
#define WT_OFF_BYTES (XPAD_ELEMS * 2)             // 27,557,888 (256B aligned)
#define KK 1152

__device__ __forceinline__ uint16_t quant_bf16(float v) {
    // round-half-even to 12 frac bits, clip to int16 range, then RNE to bf16
    float q = rintf(v * 4096.0f);
    q = fminf(fmaxf(q, -32768.0f), 32767.0f) * (1.0f / 4096.0f);
    union { float f; uint32_t u; } cv; cv.f = q;
    uint32_t u = cv.u;
    return (uint16_t)((u + 0x7fffu + ((u >> 16) & 1u)) >> 16);
}

__device__ __forceinline__ float f4c(float4 v, int k) {
    switch (k) { case 0: return v.x; case 1: return v.y;
                 case 2: return v.z; default: return v.w; }
}

// ---- transform x: NCHW f32 -> padded NHWC bf16 [32][58][58][128] ----------
// (R5 version, kept: b64 LDS writes / b128 LDS reads / 16B global stores)
__global__ __launch_bounds__(256) void quant_pad_x(const float* __restrict__ x,
                                                   uint16_t* __restrict__ xp) {
    const int b = blockIdx.x;            // one padded row (n, hp) each
    const int n = b / HP, hp = b - n * HP;
    uint16_t* row = xp + (size_t)(n * HP + hp) * HP * CIN;

    if (hp == 0 || hp == HP - 1) {       // top/bottom pad row: all zeros
        uint4 z{0, 0, 0, 0};
        uint4* d = (uint4*)row;
        for (int t = threadIdx.x; t < HP * CIN * 2 / 16; t += 256) d[t] = z;
        return;
    }
    const int h = hp - 1;
    __shared__ __align__(16) uint16_t tile[HW * 136];  // [w][c] stride 136
    const float* src = x + (size_t)n * CIN * HW * HW + (size_t)h * HW;
    for (int t = threadIdx.x; t < 32 * 14; t += 256) {
        int cg = t / 14, w4 = t - cg * 14;
        int c4 = cg * 4;
        float4 v0 = *(const float4*)(src + (size_t)(c4 + 0) * (HW * HW) + w4 * 4);
        float4 v1 = *(const float4*)(src + (size_t)(c4 + 1) * (HW * HW) + w4 * 4);
        float4 v2 = *(const float4*)(src + (size_t)(c4 + 2) * (HW * HW) + w4 * 4);
        float4 v3 = *(const float4*)(src + (size_t)(c4 + 3) * (HW * HW) + w4 * 4);
#pragma unroll
        for (int k = 0; k < 4; ++k) {
            int w = w4 * 4 + k;
            uint32_t lo = (uint32_t)quant_bf16(f4c(v0, k)) |
                          ((uint32_t)quant_bf16(f4c(v1, k)) << 16);
            uint32_t hi = (uint32_t)quant_bf16(f4c(v2, k)) |
                          ((uint32_t)quant_bf16(f4c(v3, k)) << 16);
            *(uint2*)&tile[w * 136 + c4] = make_uint2(lo, hi);
        }
    }
    __syncthreads();
    if (threadIdx.x < 32) {              // zero left/right pad pixels
        uint4 z{0, 0, 0, 0};
        if (threadIdx.x < 16) ((uint4*)row)[threadIdx.x] = z;
        else ((uint4*)(row + 57 * CIN))[threadIdx.x - 16] = z;
    }
    uint4* dst = (uint4*)(row + CIN);    // interior cols 1..56
    for (int t = threadIdx.x; t < HW * 16; t += 256) {
        int w = t >> 4, c8 = (t & 15) * 8;
        dst[t] = *(const uint4*)&tile[w * 136 + c8];
    }
}

// ---- transform w: OIHW f32 -> fragment-shuffled layout -------------------
// wt[(((kt*4+g)*4+f)*2+s)*512 + lane*8 + e] = A[row][kk]
//   row = g*64 + f*16 + (lane&15),  kk = kt*64 + s*32 + (lane>>4)*8 + e.
// One (kt,g,f,s) block = 1KB = exactly one wave's contiguous short8 load.
__global__ __launch_bounds__(256) void quant_w(const float* __restrict__ w,
                                               uint16_t* __restrict__ wt) {
    int i = blockIdx.x * 256 + threadIdx.x;   // 256*1152 = 294912 exact
    int e = i & 7;
    int lane = (i >> 3) & 63;
    int r1 = i >> 9;              // 0..575
    int s = r1 & 1;
    int f = (r1 >> 1) & 3;
    int g = (r1 >> 3) & 3;
    int kt = r1 >> 5;             // 0..17
    int row = g * 64 + f * 16 + (lane & 15);
    int kk = kt * 64 + s * 32 + (lane >> 4) * 8 + e;
    int tap = kk >> 7;            // 0..8
    int c = kk & 127;
    wt[i] = quant_bf16(w[(size_t)(row * CIN + c) * 9 + tap]);
}

// ---- main implicit GEMM ----------------------------------------------------
// LDS: ldsB[buf][128*64] bf16 (32 KiB total). Row = 128B = 8 chunks of 16B;
// slot sl at row r holds data chunk sl^(r&7) (pre-swizzled global source).
// A: direct global->register, 8 contiguous-1KB loads per wave per kt,
// double-banked raE/raO (loaded 2 K-steps ahead of use).
//
// Steady-state per K-step kt (buf b = kt&1, bank = raE/raO):
//   READ_B rb                     (8 ds_read_b128 from ldsB[b])
//   MFMA x32 (bank, rb)           (bank loaded 2 kt ago - RAW slack ~2 kt)
//   LOAD_A bank <- A(kt+2)        (8 reg-dest loads; scoreboard-tracked)
//   barrier                       (all waves done reading ldsB[b])
//   STAGE_B ldsB[b] <- B(kt+2)    (2 gload_lds)
//   vmcnt(10)                     (10 = 8 A-loads + 2 fresh stages newer than
//                                  B(kt+1) -> B(kt+1) proven landed)
//   barrier
// Never a fresh-drain vmcnt in the loop; A-loads span 2 K-steps in flight.

#define GLOAD(gsrc, ldst)                                                      \
    __builtin_amdgcn_global_load_lds(                                          \
        (__attribute__((address_space(1))) void*)(void*)(gsrc),                \
        (__attribute__((address_space(3))) void*)(void*)(ldst), 16, 0, 0)

#define STAGE_B(bsel, kt) do {                                                 \
    const int tap_ = (kt) >> 1;                                                \
    const size_t boff_ = (size_t)((tap_ / 3) * HP + (tap_ % 3)) * CIN          \
                       + (size_t)((kt) & 1) * 64;                              \
    GLOAD(bGp[0] + boff_, &ldsB[bsel][(wv * 8) * 64]);                         \
    GLOAD(bGp[1] + boff_, &ldsB[bsel][(64 + wv * 8) * 64]);                    \
} while (0)

// A fragments: contiguous 1KB per (f,s) block at the shuffled layout.
// ra[f][s][e] = A[wm*64 + f*16 + m16][kt*64 + s*32 + q*8 + e]
#define LOAD_A(RA, kt) do {                                                    \
    const uint16_t* a_ = aF + (size_t)(kt) * 16384;                            \
    _Pragma("unroll")                                                          \
    for (int f_ = 0; f_ < 4; ++f_) {                                           \
        RA[f_][0] = *(const short8*)(a_ + f_ * 1024);                          \
        RA[f_][1] = *(const short8*)(a_ + f_ * 1024 + 512);                    \
    }                                                                          \
} while (0)

#define READ_B(bsel) do {                                                      \
    _Pragma("unroll")                                                          \
    for (int fc_ = 0; fc_ < 4; ++fc_) {                                        \
        const int r_ = wn * 64 + fc_ * 16 + m16;                               \
        rb[fc_][0] = *(const short8*)&ldsB[bsel][r_ * 64 + sl0];               \
        rb[fc_][1] = *(const short8*)&ldsB[bsel][r_ * 64 + sl1];               \
    }                                                                          \
} while (0)

#define MFMA_KT(RA) do {                                                       \
    __builtin_amdgcn_s_setprio(1);                                             \
    _Pragma("unroll")                                                          \
    for (int s_ = 0; s_ < 2; ++s_)                                             \
    _Pragma("unroll")                                                          \
    for (int f_ = 0; f_ < 4; ++f_)                                             \
    _Pragma("unroll")                                                          \
    for (int c_ = 0; c_ < 4; ++c_)                                             \
        acc[f_][c_] = __builtin_amdgcn_mfma_f32_16x16x32_bf16(                 \
            RA[f_][s_], rb[c_][s_], acc[f_][c_], 0, 0, 0);                     \
    __builtin_amdgcn_s_setprio(0);                                             \
} while (0)

__global__ __launch_bounds__(512, 2) void conv_gemm(const uint16_t* __restrict__ xp,
                                                    const uint16_t* __restrict__ wt,
                                                    float* __restrict__ out) {
    __shared__ __align__(16) uint16_t ldsB[2][128 * 64];   // 32 KiB (B only)

    const int tid  = threadIdx.x;
    const int l    = tid & 63;
    const int wv   = tid >> 6;        // 0..7
    const int wm   = wv >> 1;         // 0..3: kout quarter (64 rows)
    const int wn   = wv & 1;          // 0..1: px half (64 px)
    const int srow = l >> 3;          // 0..7
    const int c_data = (l & 7) ^ srow;    // swizzled source chunk (B staging)
    const int m16  = l & 15;
    const int q    = l >> 4;          // 0..3
    const int r7   = m16 & 7;
    const int sl0  = ((0 + q) ^ r7) * 8;  // B read slot, k-half 0 (elements)
    const int sl1  = ((4 + q) ^ r7) * 8;  // B read slot, k-half 1

    const int b = blockIdx.x;                      // 0..783
    const int pxblk = (b & 7) * 98 + (b >> 3);     // XCD swizzle, 784 = 8*98

    // Per-lane A base in the fragment-shuffled weight layout:
    // block (kt,g=wm,f,s) at ((kt*4+wm)*4+f)*2+s)*512, lane offset l*8.
    const uint16_t* aF = wt + (size_t)(wm * 4 * 2) * 512 + l * 8;

    // Per-lane global staging base pointers for B (fixed across K loop).
    const uint16_t* bGp[2];
#pragma unroll
    for (int j_ = 0; j_ < 2; ++j_) {
        const int row = j_ * 64 + wv * 8 + srow;              // 0..127
        const int p = pxblk * 128 + row;                      // global px
        const int n = p / 3136; const int rem = p - n * 3136;
        const int hh = rem / HW; const int ww = rem - hh * HW;
        bGp[j_] = xp + (size_t)((n * HP + hh) * HP + ww) * CIN + c_data * 8;
    }

    floatx4 acc[4][4];
#pragma unroll
    for (int f_ = 0; f_ < 4; ++f_)
#pragma unroll
        for (int c_ = 0; c_ < 4; ++c_)
            acc[f_][c_] = (floatx4){0.f, 0.f, 0.f, 0.f};

    short8 raE[4][2];         // A bank for even kt
    short8 raO[4][2];         // A bank for odd kt
    short8 rb[4][2];          // B frags for the current kt

    // ---- prologue: stage B(0)->buf0, B(1)->buf1; load A(0), A(1).
    // vmcnt(18): B(0) landed (newer: B(1)=2 + A(0)=8 + A(1)=8).
    STAGE_B(0, 0);
    STAGE_B(1, 1);
    LOAD_A(raE, 0);
    LOAD_A(raO, 1);
    asm volatile("s_waitcnt vmcnt(18)" ::: "memory");
    __builtin_amdgcn_s_barrier();

#pragma unroll 1
    for (int it = 0; it < 8; ++it) {
        const int ktE = 2 * it;
        // ---- kt even (buf0, bank raE)
        READ_B(0);
        MFMA_KT(raE);
        LOAD_A(raE, ktE + 2);                      // for kt+2 (2-kt RAW slack)
        __builtin_amdgcn_s_barrier();              // buf0 reads complete
        STAGE_B(0, ktE + 2);
        asm volatile("s_waitcnt vmcnt(10)" ::: "memory");  // B(kt+1) landed
        __builtin_amdgcn_s_barrier();
        // ---- kt odd (buf1, bank raO)
        READ_B(1);
        MFMA_KT(raO);
        LOAD_A(raO, ktE + 3);                      // for kt+3
        __builtin_amdgcn_s_barrier();              // buf1 reads complete
        STAGE_B(1, ktE + 3);
        asm volatile("s_waitcnt vmcnt(10)" ::: "memory");  // B(kt+2) landed
        __builtin_amdgcn_s_barrier();
    }

    // ---- tail: kt16 (buf0, raE), kt17 (buf1, raO) — no more staging
    READ_B(0);
    MFMA_KT(raE);
    asm volatile("s_waitcnt vmcnt(0)" ::: "memory");       // B(17) landed
    __builtin_amdgcn_s_barrier();
    READ_B(1);
    MFMA_KT(raO);

    // ---- epilogue: D row = kout (quad*4+reg), col = px (lane&15).
    // Each fc group of 16 px stays within one image (3136 % 16 == 0).
#pragma unroll
    for (int fc = 0; fc < 4; ++fc) {
        const int p = pxblk * 128 + wn * 64 + fc * 16 + m16;
        const int n = p / 3136; const int rem = p - n * 3136;
        float* opb = out + (size_t)(n * KOUT + wm * 64) * 3136 + rem;
#pragma unroll
        for (int f = 0; f < 4; ++f) {
            const int kl = f * 16 + q * 4;
#pragma unroll
            for (int t = 0; t < 4; ++t)
                opb[(size_t)(kl + t) * 3136] = acc[f][fc][t];
        }
    }
}

extern "C" void kernel_launch(void* const* d_in, const int* in_sizes, int n_in,
                              void* d_out, int out_size, void* d_ws, size_t ws_size,
                              hipStream_t stream) {
    const float* x = (const float*)d_in[0];
    const float* w = (const float*)d_in[1];
    float* out = (float*)d_out;

    uint16_t* xp  = (uint16_t*)d_ws;                           // 27.56 MB padded bf16 x
    uint16_t* wtb = (uint16_t*)((char*)d_ws + WT_OFF_BYTES);   // 0.59 MB bf16 weights (shuffled)

    quant_pad_x<<<NIMG * HP, 256, 0, stream>>>(x, xp);         // covers ALL of xp incl. borders
    quant_w<<<(KOUT * KK) / 256, 256, 0, stream>>>(w, wtb);

    conv_gemm<<<dim3(784), dim3(512), 0, stream>>>(xp, wtb, out);
}